// Round 1
// baseline (301.928 us; speedup 1.0000x reference)
//
#include <hip/hip_runtime.h>
#include <stdint.h>
#include <math.h>

// ---------------------------------------------------------------------------
// JAX threefry2x32 (exact port of jax/_src/prng.py), usable on host + device.
// ---------------------------------------------------------------------------
__host__ __device__ static inline void tf2x32(uint32_t k0, uint32_t k1,
                                              uint32_t& x0, uint32_t& x1) {
  uint32_t ks2 = k0 ^ k1 ^ 0x1BD11BDAu;
  x0 += k0; x1 += k1;
#define TFR(r) { x0 += x1; x1 = (x1 << (r)) | (x1 >> (32 - (r))); x1 ^= x0; }
  TFR(13) TFR(15) TFR(26) TFR(6)
  x0 += k1;  x1 += ks2 + 1u;
  TFR(17) TFR(29) TFR(16) TFR(24)
  x0 += ks2; x1 += k0 + 2u;
  TFR(13) TFR(15) TFR(26) TFR(6)
  x0 += k0;  x1 += k1 + 3u;
  TFR(17) TFR(29) TFR(16) TFR(24)
  x0 += k1;  x1 += ks2 + 4u;
  TFR(13) TFR(15) TFR(26) TFR(6)
  x0 += ks2; x1 += k0 + 5u;
#undef TFR
}

struct Keys { uint32_t k[12]; };   // 6 subkeys (hi, lo) pairs

struct SampleOut { int action; float lp; float lpm; };

// ---------------------------------------------------------------------------
// One categorical sample across a 64-lane wave. Lane t holds category t.
// n <= 64 categories; lanes t >= n are padding (score = -inf, no lpm vote).
// Reproduces: gumbel (threefry partitionable bits), argmax(first-max),
// log_softmax lp at the action, and ((mask==0).sum() > 1) flag.
// ---------------------------------------------------------------------------
__device__ static inline SampleOut wave_sample(uint32_t k0, uint32_t k1,
                                               uint32_t flat_idx, int n, int t,
                                               float score, float maskval) {
  const bool active = (t < n);
  const float NEGINF = -__builtin_inff();
  float sc = active ? score : NEGINF;

  // --- gumbel noise: bits = out0 ^ out1 of threefry block (0, flat_idx) ---
  uint32_t x0 = 0u, x1 = flat_idx;
  tf2x32(k0, k1, x0, x1);
  uint32_t bits = x0 ^ x1;
  uint32_t fb = (bits >> 9) | 0x3f800000u;
  float f = __uint_as_float(fb) - 1.0f;                // [0, 1-2^-23]
  const float tinyf = 1.1754943508222875e-38f;          // f32 tiny
  float u = fmaxf(tinyf, f + tinyf);                    // jax.random.uniform
  double g = -log(-log((double)u));                     // gumbel, true-value

  double z = active ? ((double)sc + g) : (double)NEGINF;

  // --- all-reduce argmax, first-index tie-break (jnp.argmax semantics) ---
  double zv = z; int zi = t;
#pragma unroll
  for (int m = 1; m < 64; m <<= 1) {
    double ov = __shfl_xor(zv, m, 64);
    int    oi = __shfl_xor(zi, m, 64);
    if (ov > zv || (ov == zv && oi < zi)) { zv = ov; zi = oi; }
  }
  int action = zi;

  // --- log_softmax at action ---
  float mx = sc;
#pragma unroll
  for (int m = 1; m < 64; m <<= 1) mx = fmaxf(mx, __shfl_xor(mx, m, 64));
  double e = 0.0;
  if (active && sc != NEGINF) e = exp((double)sc - (double)mx);
#pragma unroll
  for (int m = 1; m < 64; m <<= 1) e += __shfl_xor(e, m, 64);
  float sa = __shfl(sc, action, 64);
  float lp = (float)(((double)sa - (double)mx) - log(e));

  // --- lpm: count of mask entries equal to 0.0 > 1 ---
  unsigned long long ball = __ballot(active && (maskval == 0.0f));
  SampleOut r;
  r.action = action;
  r.lp = lp;
  r.lpm = (__popcll(ball) > 1) ? 1.0f : 0.0f;
  return r;
}

// ---------------------------------------------------------------------------
// Main kernel: one wave per batch row. 4 waves / 256-thread block.
// ---------------------------------------------------------------------------
__global__ __launch_bounds__(256) void pt_kernel(
    const int*   __restrict__ loop_ind_p,          // [1]
    const float* __restrict__ order_mask,          // [B,O]
    const int*   __restrict__ tile_remain_budgets, // [B,L,P]
    const float* __restrict__ tile_masks,          // [B,L,P,T]
    const float* __restrict__ remain_buffer_size,  // [B]
    const int*   __restrict__ tile2_max,           // [B]
    const float* __restrict__ max_temporal_tile2,  // [B]
    const int*   __restrict__ sp_tile2_max,        // [B]
    const int*   __restrict__ sp_tile2_min,        // [B]
    const float* __restrict__ order_logit,         // [B,O]
    const float* __restrict__ tile_logits,         // [B,P,T]
    const float* __restrict__ sp_tile2_logit,      // [B,T]
    float*       __restrict__ out,                 // [21*B]
    int B, int O, int T, int P, int L, Keys keys) {
  const int wave = threadIdx.x >> 6;
  const int t    = threadIdx.x & 63;
  const int b    = blockIdx.x * (blockDim.x >> 6) + wave;
  if (b >= B) return;

  const float NEGINF = -__builtin_inff();
  const int li = loop_ind_p[0];

  // ---- order sample (keys[0]) ----
  float om = (t < O) ? order_mask[(size_t)b * O + t] : 1.0f;
  float osc = (t < O) ? (order_logit[(size_t)b * O + t] + om) : NEGINF;
  SampleOut so = wave_sample(keys.k[0], keys.k[1],
                             (uint32_t)(b * O + t), O, t, osc, om);

  // ---- sp sample (keys[1]) ----
  const float* tm_row = tile_masks + ((size_t)b * L + li) * P * T;
  float t2base = tm_row[t];                 // p = 0 row
  int spmx = sp_tile2_max[b], spmn = sp_tile2_min[b];
  float spmask = (t > spmx || t < spmn) ? NEGINF : t2base;
  float spsc = sp_tile2_logit[(size_t)b * T + t] + spmask;
  SampleOut ssp = wave_sample(keys.k[2], keys.k[3],
                              (uint32_t)(b * T + t), T, t, spsc, spmask);

  // ---- tile2 sample (keys[2]) ----
  int t2min = ssp.action;
  int mt = (int)max_temporal_tile2[b];      // trunc toward zero, values >= 0
  int t2mx = min(tile2_max[b], t2min + mt);
  float t2mask = (t > t2mx || t < t2min) ? NEGINF : t2base;
  float t2sc = tile_logits[(size_t)b * P * T + t] + t2mask;
  SampleOut st2 = wave_sample(keys.k[4], keys.k[5],
                              (uint32_t)(b * T + t), T, t, t2sc, t2mask);

  // ---- p = 1..P-1 loop (keys[2+p]) ----
  // float32-rounded np.log2(prime) (JAX x64-disabled demotion)
  const float L2P[4] = {1.0f, 1.5849625007211562f, 2.321928094887362f,
                        2.807354922057604f};
  const int PRIMES_[4] = {2, 3, 5, 7};
  int   pact[3];
  float plp[3], plpm[3];
  float rbs = remain_buffer_size[b];
  int prev = st2.action;
  for (int p = 1; p < P; ++p) {
    double pw = pow((double)PRIMES_[p - 1], (double)prev);
    rbs = (float)((double)rbs / pw);        // fp32 carry, like the reference
    double v = log2(fmax((double)rbs, 1.0)) / (double)L2P[p];
    int tmax = (int)v;                      // v >= 0
    tmax = min(T - 1, max(0, tmax));
    tmax = min(tmax, tile_remain_budgets[((size_t)b * L + li) * P + p]);
    float mask = (t > tmax) ? NEGINF : tm_row[(size_t)p * T + t];
    float sc = tile_logits[((size_t)b * P + p) * T + t] + mask;
    SampleOut s = wave_sample(keys.k[2 * (2 + p)], keys.k[2 * (2 + p) + 1],
                              (uint32_t)(b * T + t), T, t, sc, mask);
    pact[p - 1] = s.action;
    plp[p - 1]  = s.lp;
    plpm[p - 1] = s.lpm;
    prev = s.action;
  }

  // ---- write outputs (float32, concatenated in return order) ----
  if (t == 0) {
    size_t Bz = (size_t)B;
    out[b] = (float)so.action;
    float* ta = out + Bz + (size_t)b * P;       // tile_actions [B,P]
    ta[0] = (float)st2.action;
    for (int p = 1; p < P; ++p) ta[p] = (float)pact[p - 1];
    float* sa = out + Bz * (1 + P) + (size_t)b * P;  // sp_tile_actions [B,P]
    sa[0] = (float)ssp.action;
    for (int p = 1; p < P; ++p) sa[p] = 0.0f;
    int NL = 1 + P + 1;                         // 6 log-prob columns
    float* lp = out + Bz * (1 + 2 * P) + (size_t)b * NL;
    lp[0] = so.lp; lp[1] = st2.lp;
    for (int p = 1; p < P; ++p) lp[1 + p] = plp[p - 1];
    lp[NL - 1] = ssp.lp;
    float* lm = out + Bz * (1 + 2 * P + NL) + (size_t)b * NL;
    lm[0] = so.lpm; lm[1] = st2.lpm;
    for (int p = 1; p < P; ++p) lm[1 + p] = plpm[p - 1];
    lm[NL - 1] = ssp.lpm;
  }
}

// ---------------------------------------------------------------------------
extern "C" void kernel_launch(void* const* d_in, const int* in_sizes, int n_in,
                              void* d_out, int out_size, void* d_ws,
                              size_t ws_size, hipStream_t stream) {
  const int B = in_sizes[6];                 // remain_buffer_size: [B]
  const int O = in_sizes[1] / B;             // order_mask: [B,O]
  const int T = in_sizes[13] / B;            // sp_tile2_logit: [B,T]
  const int P = in_sizes[12] / (B * T);      // tile_logits: [B,P,T]
  const int L = in_sizes[2] / (B * P);       // tile_remain_budgets: [B,L,P]

  // keys = jax.random.split(jax.random.key(1), 6), threefry-partitionable
  // fold-like split: keys[j] = threefry2x32((0,1), (0, j))
  Keys keys;
  for (int j = 0; j < 6; ++j) {
    uint32_t x0 = 0u, x1 = (uint32_t)j;
    tf2x32(0u, 1u, x0, x1);
    keys.k[2 * j]     = x0;
    keys.k[2 * j + 1] = x1;
  }

  const int wavesPerBlock = 4;
  dim3 block(wavesPerBlock * 64);
  dim3 grid((B + wavesPerBlock - 1) / wavesPerBlock);
  pt_kernel<<<grid, block, 0, stream>>>(
      (const int*)d_in[5],            // loop_ind
      (const float*)d_in[1],          // order_mask
      (const int*)d_in[2],            // tile_remain_budgets
      (const float*)d_in[3],          // tile_masks
      (const float*)d_in[6],          // remain_buffer_size
      (const int*)d_in[7],            // tile2_max
      (const float*)d_in[8],          // max_temporal_tile2
      (const int*)d_in[9],            // sp_tile2_max
      (const int*)d_in[10],           // sp_tile2_min
      (const float*)d_in[11],         // order_logit
      (const float*)d_in[12],         // tile_logits
      (const float*)d_in[13],         // sp_tile2_logit
      (float*)d_out, B, O, T, P, L, keys);
}

// Round 2
// 223.952 us; speedup vs baseline: 1.3482x; 1.3482x over previous
//
#include <hip/hip_runtime.h>
#include <stdint.h>
#include <math.h>

// ---------------------------------------------------------------------------
// JAX threefry2x32 (exact port of jax/_src/prng.py), usable on host + device.
// ---------------------------------------------------------------------------
__host__ __device__ static inline void tf2x32(uint32_t k0, uint32_t k1,
                                              uint32_t& x0, uint32_t& x1) {
  uint32_t ks2 = k0 ^ k1 ^ 0x1BD11BDAu;
  x0 += k0; x1 += k1;
#define TFR(r) { x0 += x1; x1 = (x1 << (r)) | (x1 >> (32 - (r))); x1 ^= x0; }
  TFR(13) TFR(15) TFR(26) TFR(6)
  x0 += k1;  x1 += ks2 + 1u;
  TFR(17) TFR(29) TFR(16) TFR(24)
  x0 += ks2; x1 += k0 + 2u;
  TFR(13) TFR(15) TFR(26) TFR(6)
  x0 += k0;  x1 += k1 + 3u;
  TFR(17) TFR(29) TFR(16) TFR(24)
  x0 += k1;  x1 += ks2 + 4u;
  TFR(13) TFR(15) TFR(26) TFR(6)
  x0 += ks2; x1 += k0 + 5u;
#undef TFR
}

struct Keys { uint32_t k[12]; };   // 6 subkeys (hi, lo) pairs

struct SampleOut { int action; float lp; float lpm; };

// ---------------------------------------------------------------------------
// One categorical sample across a 64-lane wave, all-f32 fast path.
// Lane t holds category t; n <= 64; lanes t >= n are padding.
// gumbel bits: threefry block (0, flat_idx), bits = x0 ^ x1 (partitionable).
// argmax with first-index tie-break; lp = sc[a] - log(sum exp(sc)) (no
// max-subtract: |sc| is O(10), f32 sum can't overflow; bf16 tolerance).
// ---------------------------------------------------------------------------
__device__ static inline SampleOut wave_sample(uint32_t k0, uint32_t k1,
                                               uint32_t flat_idx, int n, int t,
                                               float score, float maskval) {
  const bool active = (t < n);
  const float NEGINF = -__builtin_inff();
  float sc = active ? score : NEGINF;

  // --- gumbel noise, f32 (reference chain is f32 end-to-end) ---
  uint32_t x0 = 0u, x1 = flat_idx;
  tf2x32(k0, k1, x0, x1);
  uint32_t bits = x0 ^ x1;
  uint32_t fb = (bits >> 9) | 0x3f800000u;
  float f = __uint_as_float(fb) - 1.0f;                 // [0, 1-2^-23]
  const float tinyf = 1.1754943508222875e-38f;          // f32 tiny
  float u = fmaxf(tinyf, f + tinyf);                    // jax.random.uniform
  float g = -logf(-logf(u));                            // gumbel

  float z  = active ? (sc + g) : NEGINF;                // -inf dominates
  float es = active ? expf(sc) : 0.0f;                  // expf(-inf) = 0

  // --- fused butterfly: argmax(z, first-index tie-break) + sum(exp) ---
  float zv = z; int zi = t;
#pragma unroll
  for (int m = 1; m < 64; m <<= 1) {
    float ov = __shfl_xor(zv, m, 64);
    int   oi = __shfl_xor(zi, m, 64);
    es += __shfl_xor(es, m, 64);
    bool take = (ov > zv) || (ov == zv && oi < zi);
    zv = take ? ov : zv;
    zi = take ? oi : zi;
  }
  int action = zi;

  float sa = __shfl(sc, action, 64);
  float lp = sa - logf(es);

  // --- lpm: count of mask entries equal to 0.0 > 1 ---
  unsigned long long ball = __ballot(active && (maskval == 0.0f));
  SampleOut r;
  r.action = action;
  r.lp = lp;
  r.lpm = (__popcll(ball) > 1) ? 1.0f : 0.0f;
  return r;
}

// exact-ish prime^e via repeated squaring in double (replaces dpow)
__device__ static inline double ipow_d(int base, int e) {
  double r = 1.0, b = (double)base;
  while (e) { if (e & 1) r *= b; b *= b; e >>= 1; }
  return r;
}

// ---------------------------------------------------------------------------
// Main kernel: one wave per batch row. 4 waves / 256-thread block.
// ---------------------------------------------------------------------------
__global__ __launch_bounds__(256) void pt_kernel(
    const int*   __restrict__ loop_ind_p,          // [1]
    const float* __restrict__ order_mask,          // [B,O]
    const int*   __restrict__ tile_remain_budgets, // [B,L,P]
    const float* __restrict__ tile_masks,          // [B,L,P,T]
    const float* __restrict__ remain_buffer_size,  // [B]
    const int*   __restrict__ tile2_max,           // [B]
    const float* __restrict__ max_temporal_tile2,  // [B]
    const int*   __restrict__ sp_tile2_max,        // [B]
    const int*   __restrict__ sp_tile2_min,        // [B]
    const float* __restrict__ order_logit,         // [B,O]
    const float* __restrict__ tile_logits,         // [B,P,T]
    const float* __restrict__ sp_tile2_logit,      // [B,T]
    float*       __restrict__ out,                 // [21*B]
    int B, int O, int T, int P, int L, Keys keys) {
  const int wave = threadIdx.x >> 6;
  const int t    = threadIdx.x & 63;
  const int b    = blockIdx.x * (blockDim.x >> 6) + wave;
  if (b >= B) return;

  const float NEGINF = -__builtin_inff();
  const int li = loop_ind_p[0];

  // ---- order sample (keys[0]) ----
  float om = (t < O) ? order_mask[(size_t)b * O + t] : 1.0f;
  float osc = (t < O) ? (order_logit[(size_t)b * O + t] + om) : NEGINF;
  SampleOut so = wave_sample(keys.k[0], keys.k[1],
                             (uint32_t)(b * O + t), O, t, osc, om);

  // ---- sp sample (keys[1]) ----
  const float* tm_row = tile_masks + ((size_t)b * L + li) * P * T;
  float t2base = tm_row[t];                 // p = 0 row
  int spmx = sp_tile2_max[b], spmn = sp_tile2_min[b];
  float spmask = (t > spmx || t < spmn) ? NEGINF : t2base;
  float spsc = sp_tile2_logit[(size_t)b * T + t] + spmask;
  SampleOut ssp = wave_sample(keys.k[2], keys.k[3],
                              (uint32_t)(b * T + t), T, t, spsc, spmask);

  // ---- tile2 sample (keys[2]) ----
  int t2min = ssp.action;
  int mt = (int)max_temporal_tile2[b];      // trunc toward zero, values >= 0
  int t2mx = min(tile2_max[b], t2min + mt);
  float t2mask = (t > t2mx || t < t2min) ? NEGINF : t2base;
  float t2sc = tile_logits[(size_t)b * P * T + t] + t2mask;
  SampleOut st2 = wave_sample(keys.k[4], keys.k[5],
                              (uint32_t)(b * T + t), T, t, t2sc, t2mask);

  // ---- p = 1..P-1 loop (keys[2+p]) ----
  // float32-rounded np.log2(prime) (JAX x64-disabled demotion)
  const float L2P[4] = {1.0f, 1.5849625007211562f, 2.321928094887362f,
                        2.807354922057604f};
  const int PRIMES_[4] = {2, 3, 5, 7};
  int   pact[3];
  float plp[3], plpm[3];
  float rbs = remain_buffer_size[b];
  int prev = st2.action;
  for (int p = 1; p < P; ++p) {
    double pw = ipow_d(PRIMES_[p - 1], prev);
    rbs = (float)((double)rbs / pw);        // fp32 carry, like the reference
    double v = log2(fmax((double)rbs, 1.0)) / (double)L2P[p];
    int tmax = (int)v;                      // v >= 0
    tmax = min(T - 1, max(0, tmax));
    tmax = min(tmax, tile_remain_budgets[((size_t)b * L + li) * P + p]);
    float mask = (t > tmax) ? NEGINF : tm_row[(size_t)p * T + t];
    float sc = tile_logits[((size_t)b * P + p) * T + t] + mask;
    SampleOut s = wave_sample(keys.k[2 * (2 + p)], keys.k[2 * (2 + p) + 1],
                              (uint32_t)(b * T + t), T, t, sc, mask);
    pact[p - 1] = s.action;
    plp[p - 1]  = s.lp;
    plpm[p - 1] = s.lpm;
    prev = s.action;
  }

  // ---- write outputs (float32, concatenated in return order) ----
  if (t == 0) {
    size_t Bz = (size_t)B;
    out[b] = (float)so.action;
    float* ta = out + Bz + (size_t)b * P;       // tile_actions [B,P]
    ta[0] = (float)st2.action;
    for (int p = 1; p < P; ++p) ta[p] = (float)pact[p - 1];
    float* sa = out + Bz * (1 + P) + (size_t)b * P;  // sp_tile_actions [B,P]
    sa[0] = (float)ssp.action;
    for (int p = 1; p < P; ++p) sa[p] = 0.0f;
    int NL = 1 + P + 1;                         // 6 log-prob columns
    float* lp = out + Bz * (1 + 2 * P) + (size_t)b * NL;
    lp[0] = so.lp; lp[1] = st2.lp;
    for (int p = 1; p < P; ++p) lp[1 + p] = plp[p - 1];
    lp[NL - 1] = ssp.lp;
    float* lm = out + Bz * (1 + 2 * P + NL) + (size_t)b * NL;
    lm[0] = so.lpm; lm[1] = st2.lpm;
    for (int p = 1; p < P; ++p) lm[1 + p] = plpm[p - 1];
    lm[NL - 1] = ssp.lpm;
  }
}

// ---------------------------------------------------------------------------
extern "C" void kernel_launch(void* const* d_in, const int* in_sizes, int n_in,
                              void* d_out, int out_size, void* d_ws,
                              size_t ws_size, hipStream_t stream) {
  const int B = in_sizes[6];                 // remain_buffer_size: [B]
  const int O = in_sizes[1] / B;             // order_mask: [B,O]
  const int T = in_sizes[13] / B;            // sp_tile2_logit: [B,T]
  const int P = in_sizes[12] / (B * T);      // tile_logits: [B,P,T]
  const int L = in_sizes[2] / (B * P);       // tile_remain_budgets: [B,L,P]

  // keys = jax.random.split(jax.random.key(1), 6), threefry-partitionable
  // fold-like split: keys[j] = threefry2x32((0,1), (0, j))
  Keys keys;
  for (int j = 0; j < 6; ++j) {
    uint32_t x0 = 0u, x1 = (uint32_t)j;
    tf2x32(0u, 1u, x0, x1);
    keys.k[2 * j]     = x0;
    keys.k[2 * j + 1] = x1;
  }

  const int wavesPerBlock = 4;
  dim3 block(wavesPerBlock * 64);
  dim3 grid((B + wavesPerBlock - 1) / wavesPerBlock);
  pt_kernel<<<grid, block, 0, stream>>>(
      (const int*)d_in[5],            // loop_ind
      (const float*)d_in[1],          // order_mask
      (const int*)d_in[2],            // tile_remain_budgets
      (const float*)d_in[3],          // tile_masks
      (const float*)d_in[6],          // remain_buffer_size
      (const int*)d_in[7],            // tile2_max
      (const float*)d_in[8],          // max_temporal_tile2
      (const int*)d_in[9],            // sp_tile2_max
      (const int*)d_in[10],           // sp_tile2_min
      (const float*)d_in[11],         // order_logit
      (const float*)d_in[12],         // tile_logits
      (const float*)d_in[13],         // sp_tile2_logit
      (float*)d_out, B, O, T, P, L, keys);
}

// Round 3
// 214.645 us; speedup vs baseline: 1.4066x; 1.0434x over previous
//
#include <hip/hip_runtime.h>
#include <stdint.h>
#include <math.h>

// ---------------------------------------------------------------------------
// JAX threefry2x32 (exact port of jax/_src/prng.py), usable on host + device.
// ---------------------------------------------------------------------------
__host__ __device__ static inline void tf2x32(uint32_t k0, uint32_t k1,
                                              uint32_t& x0, uint32_t& x1) {
  uint32_t ks2 = k0 ^ k1 ^ 0x1BD11BDAu;
  x0 += k0; x1 += k1;
#define TFR(r) { x0 += x1; x1 = (x1 << (r)) | (x1 >> (32 - (r))); x1 ^= x0; }
  TFR(13) TFR(15) TFR(26) TFR(6)
  x0 += k1;  x1 += ks2 + 1u;
  TFR(17) TFR(29) TFR(16) TFR(24)
  x0 += ks2; x1 += k0 + 2u;
  TFR(13) TFR(15) TFR(26) TFR(6)
  x0 += k0;  x1 += k1 + 3u;
  TFR(17) TFR(29) TFR(16) TFR(24)
  x0 += k1;  x1 += ks2 + 4u;
  TFR(13) TFR(15) TFR(26) TFR(6)
  x0 += ks2; x1 += k0 + 5u;
#undef TFR
}

struct Keys { uint32_t k[12]; };   // 6 subkeys (hi, lo) pairs

struct SampleOut { int action; float lp; float lpm; };

// ---------------------------------------------------------------------------
// DPP wave64 reductions (rocPRIM pattern: row_shr 1/2/4/8, row_bcast 15/31;
// full reduction lands in lane 63, then readlane broadcasts via SGPR).
// Pure VALU — no DS-pipe ds_swizzle like __shfl_xor lowers to.
// ---------------------------------------------------------------------------
template <int CTRL>
__device__ __forceinline__ float dpp_max_step(float v) {
  // old = v: invalid source lanes yield own value -> identity for max
  int o = __builtin_amdgcn_update_dpp(__float_as_int(v), __float_as_int(v),
                                      CTRL, 0xf, 0xf, false);
  return fmaxf(v, __int_as_float(o));
}
template <int CTRL>
__device__ __forceinline__ float dpp_add_step(float v) {
  // old = 0: invalid source lanes contribute 0 -> identity for add
  int o = __builtin_amdgcn_update_dpp(0, __float_as_int(v),
                                      CTRL, 0xf, 0xf, false);
  return v + __int_as_float(o);
}
__device__ __forceinline__ float wave_max_bcast(float v) {
  v = dpp_max_step<0x111>(v);   // row_shr:1
  v = dpp_max_step<0x112>(v);   // row_shr:2
  v = dpp_max_step<0x114>(v);   // row_shr:4
  v = dpp_max_step<0x118>(v);   // row_shr:8
  v = dpp_max_step<0x142>(v);   // row_bcast:15
  v = dpp_max_step<0x143>(v);   // row_bcast:31
  return __int_as_float(__builtin_amdgcn_readlane(__float_as_int(v), 63));
}
__device__ __forceinline__ float wave_sum_bcast(float v) {
  v = dpp_add_step<0x111>(v);
  v = dpp_add_step<0x112>(v);
  v = dpp_add_step<0x114>(v);
  v = dpp_add_step<0x118>(v);
  v = dpp_add_step<0x142>(v);
  v = dpp_add_step<0x143>(v);
  return __int_as_float(__builtin_amdgcn_readlane(__float_as_int(v), 63));
}

// ---------------------------------------------------------------------------
// Categorical sample from pre-masked z (= score + gumbel, -inf where masked)
// and es (= exp(score), 0 where masked). sc_full is the UNMASKED score
// vector (only read at the argmax lane, which is always a valid lane).
// argmax first-index tie-break == ffs of (z == max) ballot.
// ---------------------------------------------------------------------------
__device__ static inline SampleOut sample_pre(float z, float es, float sc_full,
                                              bool lpm_pred) {
  float zmax = wave_max_bcast(z);
  unsigned long long ball = __ballot(z == zmax);
  int action = __ffsll(ball) - 1;
  float essum = wave_sum_bcast(es);
  float sa = __int_as_float(
      __builtin_amdgcn_readlane(__float_as_int(sc_full), action));
  unsigned long long mb = __ballot(lpm_pred);
  SampleOut r;
  r.action = action;
  r.lp = sa - logf(essum);
  r.lpm = (__popcll(mb) > 1) ? 1.0f : 0.0f;
  return r;
}

// exact prime^e via repeated squaring in double (e in [0,63])
__device__ static inline double ipow_d(int base, int e) {
  double r = 1.0, b = (double)base;
#pragma unroll
  for (int i = 0; i < 6; ++i) {
    if (e & (1 << i)) r *= b;
    b *= b;
  }
  return r;
}

// gumbel from threefry block (0, flat_idx), bits = x0 ^ x1 (partitionable)
__device__ static inline float gumbel_f(uint32_t k0, uint32_t k1,
                                        uint32_t flat_idx) {
  uint32_t x0 = 0u, x1 = flat_idx;
  tf2x32(k0, k1, x0, x1);
  uint32_t bits = x0 ^ x1;
  uint32_t fb = (bits >> 9) | 0x3f800000u;
  float f = __uint_as_float(fb) - 1.0f;                 // [0, 1-2^-23]
  const float tinyf = 1.1754943508222875e-38f;          // f32 tiny
  float u = fmaxf(tinyf, f + tinyf);                    // jax.random.uniform
  return -logf(-logf(u));
}

// ---------------------------------------------------------------------------
// Main kernel: one wave per batch row. 4 waves / 256-thread block.
// ---------------------------------------------------------------------------
__global__ __launch_bounds__(256) void pt_kernel(
    const int*   __restrict__ loop_ind_p,          // [1]
    const float* __restrict__ order_mask,          // [B,O]
    const int*   __restrict__ tile_remain_budgets, // [B,L,P]
    const float* __restrict__ tile_masks,          // [B,L,P,T]
    const float* __restrict__ remain_buffer_size,  // [B]
    const int*   __restrict__ tile2_max,           // [B]
    const float* __restrict__ max_temporal_tile2,  // [B]
    const int*   __restrict__ sp_tile2_max,        // [B]
    const int*   __restrict__ sp_tile2_min,        // [B]
    const float* __restrict__ order_logit,         // [B,O]
    const float* __restrict__ tile_logits,         // [B,P,T]
    const float* __restrict__ sp_tile2_logit,      // [B,T]
    float*       __restrict__ out,                 // [21*B]
    int B, int O, int T, int P, int L, Keys keys) {
  const int wave = threadIdx.x >> 6;
  const int t    = threadIdx.x & 63;
  const int b    = blockIdx.x * (blockDim.x >> 6) + wave;
  if (b >= B) return;

  const float NEGINF = -__builtin_inff();
  const int li = loop_ind_p[0];

  // ================= action-independent precompute (full ILP) =============
  // 6 gumbels — 6 independent threefry hashes
  float g0 = gumbel_f(keys.k[0],  keys.k[1],  (uint32_t)(b * O + t));
  uint32_t fT = (uint32_t)(b * T + t);
  float g1 = gumbel_f(keys.k[2],  keys.k[3],  fT);   // sp
  float g2 = gumbel_f(keys.k[4],  keys.k[5],  fT);   // tile2
  float g3 = gumbel_f(keys.k[6],  keys.k[7],  fT);   // p=1
  float g4 = gumbel_f(keys.k[8],  keys.k[9],  fT);   // p=2
  float g5 = gumbel_f(keys.k[10], keys.k[11], fT);   // p=3

  // order stage (independent of everything)
  float om  = (t < O) ? order_mask[(size_t)b * O + t] : 1.0f;
  float osc = (t < O) ? (order_logit[(size_t)b * O + t] + om) : NEGINF;

  // tile-mask row and logits for all stages
  const float* tm_row = tile_masks + ((size_t)b * L + li) * P * T;
  const float* tl_row = tile_logits + (size_t)b * P * T;
  float base0 = tm_row[t];
  float base1 = tm_row[T + t];
  float base2 = tm_row[2 * T + t];
  float base3 = tm_row[3 * T + t];

  // sp stage: mask known upfront
  int spmx = sp_tile2_max[b], spmn = sp_tile2_min[b];
  float spmask = (t > spmx || t < spmn) ? NEGINF : base0;
  float spsc   = sp_tile2_logit[(size_t)b * T + t] + spmask;

  // unmasked scores + exp for the action-dependent stages
  float sc2f = tl_row[t]         + base0;   // tile2 (p=0 logits, base0)
  float sc3f = tl_row[T + t]     + base1;   // p=1
  float sc4f = tl_row[2 * T + t] + base2;   // p=2
  float sc5f = tl_row[3 * T + t] + base3;   // p=3
  float es2f = expf(sc2f), es3f = expf(sc3f);
  float es4f = expf(sc4f), es5f = expf(sc5f);
  float z2f = sc2f + g2, z3f = sc3f + g3, z4f = sc4f + g4, z5f = sc5f + g5;

  // budgets p=1..3 are contiguous ints
  const int* budg = tile_remain_budgets + ((size_t)b * L + li) * P;

  // ================= order sample (no deps) ================================
  SampleOut so = sample_pre(osc + g0, expf(osc), osc,
                            (t < O) && (om == 0.0f));

  // ================= sp sample =============================================
  SampleOut ssp = sample_pre(spsc + g1, expf(spsc), spsc, spmask == 0.0f);

  // ================= tile2 sample (depends on sp action) ===================
  int t2min = ssp.action;
  int mt = (int)max_temporal_tile2[b];      // trunc toward zero, >= 0
  int t2mx = min(tile2_max[b], t2min + mt);
  bool pv2 = (t <= t2mx) && (t >= t2min);
  SampleOut st2 = sample_pre(pv2 ? z2f : NEGINF, pv2 ? es2f : 0.0f, sc2f,
                             pv2 && (base0 == 0.0f));

  // ================= p = 1..3 chain ========================================
  // float32-rounded np.log2(prime) divisors (JAX x64-disabled demotion)
  const float L2P1 = 1.5849625007211562f;   // log2(3)
  const float L2P2 = 2.321928094887362f;    // log2(5)
  const float L2P3 = 2.807354922057604f;    // log2(7)

  float rbs = remain_buffer_size[b];
  int   pact[3];
  float plp[3], plpm[3];

  int prev = st2.action;
  {  // p = 1 (divide by 2^prev, divisor log2(3))
    rbs = (float)((double)rbs / ipow_d(2, prev));
    double v = log2(fmax((double)rbs, 1.0)) / (double)L2P1;
    int tmax = min(T - 1, max(0, (int)v));
    tmax = min(tmax, budg[1]);
    bool pv = (t <= tmax);
    SampleOut s = sample_pre(pv ? z3f : NEGINF, pv ? es3f : 0.0f, sc3f,
                             pv && (base1 == 0.0f));
    pact[0] = s.action; plp[0] = s.lp; plpm[0] = s.lpm; prev = s.action;
  }
  {  // p = 2 (divide by 3^prev, divisor log2(5))
    rbs = (float)((double)rbs / ipow_d(3, prev));
    double v = log2(fmax((double)rbs, 1.0)) / (double)L2P2;
    int tmax = min(T - 1, max(0, (int)v));
    tmax = min(tmax, budg[2]);
    bool pv = (t <= tmax);
    SampleOut s = sample_pre(pv ? z4f : NEGINF, pv ? es4f : 0.0f, sc4f,
                             pv && (base2 == 0.0f));
    pact[1] = s.action; plp[1] = s.lp; plpm[1] = s.lpm; prev = s.action;
  }
  {  // p = 3 (divide by 5^prev, divisor log2(7))
    rbs = (float)((double)rbs / ipow_d(5, prev));
    double v = log2(fmax((double)rbs, 1.0)) / (double)L2P3;
    int tmax = min(T - 1, max(0, (int)v));
    tmax = min(tmax, budg[3]);
    bool pv = (t <= tmax);
    SampleOut s = sample_pre(pv ? z5f : NEGINF, pv ? es5f : 0.0f, sc5f,
                             pv && (base3 == 0.0f));
    pact[2] = s.action; plp[2] = s.lp; plpm[2] = s.lpm;
  }

  // ================= write outputs (float32, return order) ================
  if (t == 0) {
    size_t Bz = (size_t)B;
    out[b] = (float)so.action;
    float* ta = out + Bz + (size_t)b * P;            // tile_actions [B,P]
    ta[0] = (float)st2.action;
    ta[1] = (float)pact[0]; ta[2] = (float)pact[1]; ta[3] = (float)pact[2];
    float* sa = out + Bz * (1 + P) + (size_t)b * P;  // sp_tile_actions [B,P]
    sa[0] = (float)ssp.action; sa[1] = 0.0f; sa[2] = 0.0f; sa[3] = 0.0f;
    const int NL = 6;                                // 1 + P + 1
    float* lp = out + Bz * (1 + 2 * P) + (size_t)b * NL;
    lp[0] = so.lp; lp[1] = st2.lp;
    lp[2] = plp[0]; lp[3] = plp[1]; lp[4] = plp[2];
    lp[5] = ssp.lp;
    float* lm = out + Bz * (1 + 2 * P + NL) + (size_t)b * NL;
    lm[0] = so.lpm; lm[1] = st2.lpm;
    lm[2] = plpm[0]; lm[3] = plpm[1]; lm[4] = plpm[2];
    lm[5] = ssp.lpm;
  }
}

// ---------------------------------------------------------------------------
extern "C" void kernel_launch(void* const* d_in, const int* in_sizes, int n_in,
                              void* d_out, int out_size, void* d_ws,
                              size_t ws_size, hipStream_t stream) {
  const int B = in_sizes[6];                 // remain_buffer_size: [B]
  const int O = in_sizes[1] / B;             // order_mask: [B,O]
  const int T = in_sizes[13] / B;            // sp_tile2_logit: [B,T]
  const int P = in_sizes[12] / (B * T);      // tile_logits: [B,P,T]
  const int L = in_sizes[2] / (B * P);       // tile_remain_budgets: [B,L,P]

  // keys = jax.random.split(jax.random.key(1), 6), threefry-partitionable
  // fold-like split: keys[j] = threefry2x32((0,1), (0, j))
  Keys keys;
  for (int j = 0; j < 6; ++j) {
    uint32_t x0 = 0u, x1 = (uint32_t)j;
    tf2x32(0u, 1u, x0, x1);
    keys.k[2 * j]     = x0;
    keys.k[2 * j + 1] = x1;
  }

  const int wavesPerBlock = 4;
  dim3 block(wavesPerBlock * 64);
  dim3 grid((B + wavesPerBlock - 1) / wavesPerBlock);
  pt_kernel<<<grid, block, 0, stream>>>(
      (const int*)d_in[5],            // loop_ind
      (const float*)d_in[1],          // order_mask
      (const int*)d_in[2],            // tile_remain_budgets
      (const float*)d_in[3],          // tile_masks
      (const float*)d_in[6],          // remain_buffer_size
      (const int*)d_in[7],            // tile2_max
      (const float*)d_in[8],          // max_temporal_tile2
      (const int*)d_in[9],            // sp_tile2_max
      (const int*)d_in[10],           // sp_tile2_min
      (const float*)d_in[11],         // order_logit
      (const float*)d_in[12],         // tile_logits
      (const float*)d_in[13],         // sp_tile2_logit
      (float*)d_out, B, O, T, P, L, keys);
}

// Round 4
// 206.879 us; speedup vs baseline: 1.4594x; 1.0375x over previous
//
#include <hip/hip_runtime.h>
#include <stdint.h>
#include <math.h>

// ---------------------------------------------------------------------------
// JAX threefry2x32 (exact port of jax/_src/prng.py), usable on host + device.
// ---------------------------------------------------------------------------
__host__ __device__ static inline void tf2x32(uint32_t k0, uint32_t k1,
                                              uint32_t& x0, uint32_t& x1) {
  uint32_t ks2 = k0 ^ k1 ^ 0x1BD11BDAu;
  x0 += k0; x1 += k1;
#define TFR(r) { x0 += x1; x1 = (x1 << (r)) | (x1 >> (32 - (r))); x1 ^= x0; }
  TFR(13) TFR(15) TFR(26) TFR(6)
  x0 += k1;  x1 += ks2 + 1u;
  TFR(17) TFR(29) TFR(16) TFR(24)
  x0 += ks2; x1 += k0 + 2u;
  TFR(13) TFR(15) TFR(26) TFR(6)
  x0 += k0;  x1 += k1 + 3u;
  TFR(17) TFR(29) TFR(16) TFR(24)
  x0 += k1;  x1 += ks2 + 4u;
  TFR(13) TFR(15) TFR(26) TFR(6)
  x0 += ks2; x1 += k0 + 5u;
#undef TFR
}

struct Keys { uint32_t k[12]; };   // 6 subkeys (hi, lo) pairs

struct SampleOut { int action; float lp; float lpm; };

// ---------------------------------------------------------------------------
// constexpr tables: thresholds T[k] = 2^(k * l2p) and inverse prime powers.
// tmax = floor(log2(x)/l2p) = #{k in 1..63 : T[k] <= x}  (x >= 1).
// CEXP2: Taylor e^(f ln2) * 2^i, rel err ~3e-15 — equivalent to the
// previously-passing double log2/div chain except on a ~1e-15-measure set.
// ---------------------------------------------------------------------------
struct DTab { double v[64]; };

constexpr double CEXP2(double w) {           // w >= 0
  long i = (long)w;                          // floor (w >= 0)
  double f = w - (double)i;
  double y = f * 0.69314718055994530941723212145818;  // ln2
  double term = 1.0, sum = 1.0;
  for (int k = 1; k <= 18; ++k) { term = term * y / (double)k; sum += term; }
  double p = 1.0;
  for (long k = 0; k < i; ++k) p *= 2.0;     // exact
  return sum * p;
}
constexpr DTab make_thresh(double l2p) {
  DTab t{};
  t.v[0] = 1e300;                            // lane 0 never counts
  for (int k = 1; k < 64; ++k) t.v[k] = CEXP2((double)k * l2p);
  return t;
}
constexpr DTab make_invpw(int p) {
  DTab t{};
  double pw = 1.0;
  for (int k = 0; k < 64; ++k) { t.v[k] = 1.0 / pw; pw *= (double)p; }
  return t;
}
// float32-rounded np.log2(prime) divisors (JAX x64-disabled demotion)
__constant__ DTab THR3 = make_thresh((double)1.5849625007211562f);  // log2(3)
__constant__ DTab THR5 = make_thresh((double)2.321928094887362f);   // log2(5)
__constant__ DTab THR7 = make_thresh((double)2.807354922057604f);   // log2(7)
__constant__ DTab IPW2 = make_invpw(2);
__constant__ DTab IPW3 = make_invpw(3);
__constant__ DTab IPW5 = make_invpw(5);

// ---------------------------------------------------------------------------
// DPP wave64 reductions (row_shr 1/2/4/8, row_bcast 15/31; lane 63 holds
// the result; readlane broadcasts via SGPR). Pure VALU.
// ---------------------------------------------------------------------------
template <int CTRL>
__device__ __forceinline__ float dpp_max_step(float v) {
  int o = __builtin_amdgcn_update_dpp(__float_as_int(v), __float_as_int(v),
                                      CTRL, 0xf, 0xf, false);
  return fmaxf(v, __int_as_float(o));
}
template <int CTRL>
__device__ __forceinline__ float dpp_add_step(float v) {
  int o = __builtin_amdgcn_update_dpp(0, __float_as_int(v),
                                      CTRL, 0xf, 0xf, false);
  return v + __int_as_float(o);
}
__device__ __forceinline__ float wave_max_bcast(float v) {
  v = dpp_max_step<0x111>(v);
  v = dpp_max_step<0x112>(v);
  v = dpp_max_step<0x114>(v);
  v = dpp_max_step<0x118>(v);
  v = dpp_max_step<0x142>(v);
  v = dpp_max_step<0x143>(v);
  return __int_as_float(__builtin_amdgcn_readlane(__float_as_int(v), 63));
}
__device__ __forceinline__ float wave_sum_bcast(float v) {
  v = dpp_add_step<0x111>(v);
  v = dpp_add_step<0x112>(v);
  v = dpp_add_step<0x114>(v);
  v = dpp_add_step<0x118>(v);
  v = dpp_add_step<0x142>(v);
  v = dpp_add_step<0x143>(v);
  return __int_as_float(__builtin_amdgcn_readlane(__float_as_int(v), 63));
}

__device__ __forceinline__ double readlane_d(double v, int lane) {
  union { double d; int i[2]; } u, r;
  u.d = v;
  r.i[0] = __builtin_amdgcn_readlane(u.i[0], lane);
  r.i[1] = __builtin_amdgcn_readlane(u.i[1], lane);
  return r.d;
}

// ---------------------------------------------------------------------------
// Categorical sample from pre-masked z (score+gumbel, -inf masked) and es
// (exp(score), 0 masked). sc_full: unmasked scores (read at argmax lane).
// argmax first-index tie-break == ffs of (z == max) ballot.
// ---------------------------------------------------------------------------
__device__ static inline SampleOut sample_pre(float z, float es, float sc_full,
                                              bool lpm_pred) {
  float zmax = wave_max_bcast(z);
  unsigned long long ball = __ballot(z == zmax);
  int action = __builtin_amdgcn_readfirstlane(__ffsll(ball) - 1);
  float essum = wave_sum_bcast(es);
  float sa = __int_as_float(
      __builtin_amdgcn_readlane(__float_as_int(sc_full), action));
  unsigned long long mb = __ballot(lpm_pred);
  SampleOut r;
  r.action = action;
  r.lp = sa - logf(essum);
  r.lpm = (__popcll(mb) > 1) ? 1.0f : 0.0f;
  return r;
}

// gumbel from threefry block (0, flat_idx), bits = x0 ^ x1 (partitionable)
__device__ static inline float gumbel_f(uint32_t k0, uint32_t k1,
                                        uint32_t flat_idx) {
  uint32_t x0 = 0u, x1 = flat_idx;
  tf2x32(k0, k1, x0, x1);
  uint32_t bits = x0 ^ x1;
  uint32_t fb = (bits >> 9) | 0x3f800000u;
  float f = __uint_as_float(fb) - 1.0f;                 // [0, 1-2^-23]
  const float tinyf = 1.1754943508222875e-38f;          // f32 tiny
  float u = fmaxf(tinyf, f + tinyf);                    // jax.random.uniform
  return -logf(-logf(u));
}

// ---------------------------------------------------------------------------
// Main kernel: one wave per batch row. 4 waves / 256-thread block.
// ---------------------------------------------------------------------------
__global__ __launch_bounds__(256) void pt_kernel(
    const int*   __restrict__ loop_ind_p,          // [1]
    const float* __restrict__ order_mask,          // [B,O]
    const int*   __restrict__ tile_remain_budgets, // [B,L,P]
    const float* __restrict__ tile_masks,          // [B,L,P,T]
    const float* __restrict__ remain_buffer_size,  // [B]
    const int*   __restrict__ tile2_max,           // [B]
    const float* __restrict__ max_temporal_tile2,  // [B]
    const int*   __restrict__ sp_tile2_max,        // [B]
    const int*   __restrict__ sp_tile2_min,        // [B]
    const float* __restrict__ order_logit,         // [B,O]
    const float* __restrict__ tile_logits,         // [B,P,T]
    const float* __restrict__ sp_tile2_logit,      // [B,T]
    float*       __restrict__ out,                 // [21*B]
    int B, int O, int T, int P, int L, Keys keys) {
  const int wave = threadIdx.x >> 6;
  const int t    = threadIdx.x & 63;
  const int b    = blockIdx.x * (blockDim.x >> 6) + wave;
  if (b >= B) return;

  const float NEGINF = -__builtin_inff();
  const int li = loop_ind_p[0];

  // ================= per-lane constant tables ==============================
  double thr3 = THR3.v[t], thr5 = THR5.v[t], thr7 = THR7.v[t];
  double ipw2 = IPW2.v[t], ipw3 = IPW3.v[t], ipw5 = IPW5.v[t];

  // ================= action-independent precompute (full ILP) =============
  float g0 = gumbel_f(keys.k[0],  keys.k[1],  (uint32_t)(b * O + t));
  uint32_t fT = (uint32_t)(b * T + t);
  float g1 = gumbel_f(keys.k[2],  keys.k[3],  fT);   // sp
  float g2 = gumbel_f(keys.k[4],  keys.k[5],  fT);   // tile2
  float g3 = gumbel_f(keys.k[6],  keys.k[7],  fT);   // p=1
  float g4 = gumbel_f(keys.k[8],  keys.k[9],  fT);   // p=2
  float g5 = gumbel_f(keys.k[10], keys.k[11], fT);   // p=3

  float om  = (t < O) ? order_mask[(size_t)b * O + t] : 1.0f;
  float osc = (t < O) ? (order_logit[(size_t)b * O + t] + om) : NEGINF;

  const float* tm_row = tile_masks + ((size_t)b * L + li) * P * T;
  const float* tl_row = tile_logits + (size_t)b * P * T;
  float base0 = tm_row[t];
  float base1 = tm_row[T + t];
  float base2 = tm_row[2 * T + t];
  float base3 = tm_row[3 * T + t];

  int spmx = sp_tile2_max[b], spmn = sp_tile2_min[b];
  float spmask = (t > spmx || t < spmn) ? NEGINF : base0;
  float spsc   = sp_tile2_logit[(size_t)b * T + t] + spmask;

  float sc2f = tl_row[t]         + base0;   // tile2 (p=0)
  float sc3f = tl_row[T + t]     + base1;   // p=1
  float sc4f = tl_row[2 * T + t] + base2;   // p=2
  float sc5f = tl_row[3 * T + t] + base3;   // p=3
  float es2f = expf(sc2f), es3f = expf(sc3f);
  float es4f = expf(sc4f), es5f = expf(sc5f);
  float z2f = sc2f + g2, z3f = sc3f + g3, z4f = sc4f + g4, z5f = sc5f + g5;

  const int* budg = tile_remain_budgets + ((size_t)b * L + li) * P;
  int bu1 = budg[1], bu2 = budg[2], bu3 = budg[3];
  int t2maxcap = tile2_max[b];
  int mt = (int)max_temporal_tile2[b];      // trunc toward zero, >= 0
  float rbs = remain_buffer_size[b];

  // ================= order sample (no deps) ================================
  SampleOut so = sample_pre(osc + g0, expf(osc), osc,
                            (t < O) && (om == 0.0f));

  // ================= sp sample =============================================
  SampleOut ssp = sample_pre(spsc + g1, expf(spsc), spsc, spmask == 0.0f);

  // ================= tile2 sample (depends on sp action) ===================
  int t2min = ssp.action;
  int t2mx = min(t2maxcap, t2min + mt);
  bool pv2 = (t <= t2mx) && (t >= t2min);
  SampleOut st2 = sample_pre(pv2 ? z2f : NEGINF, pv2 ? es2f : 0.0f, sc2f,
                             pv2 && (base0 == 0.0f));

  // ================= p = 1..3 chain (threshold tables) =====================
  int   pact[3];
  float plp[3], plpm[3];

  int prev = st2.action;
  {  // p = 1: divide by 2^prev, thresholds 2^(k*log2f(3))
    rbs = (float)((double)rbs * readlane_d(ipw2, prev));
    double x = (double)fmaxf(rbs, 1.0f);
    int tmax = min((int)__popcll(__ballot(x >= thr3)), bu1);
    bool pv = (t <= tmax);
    SampleOut s = sample_pre(pv ? z3f : NEGINF, pv ? es3f : 0.0f, sc3f,
                             pv && (base1 == 0.0f));
    pact[0] = s.action; plp[0] = s.lp; plpm[0] = s.lpm; prev = s.action;
  }
  {  // p = 2: divide by 3^prev, thresholds 2^(k*log2f(5))
    rbs = (float)((double)rbs * readlane_d(ipw3, prev));
    double x = (double)fmaxf(rbs, 1.0f);
    int tmax = min((int)__popcll(__ballot(x >= thr5)), bu2);
    bool pv = (t <= tmax);
    SampleOut s = sample_pre(pv ? z4f : NEGINF, pv ? es4f : 0.0f, sc4f,
                             pv && (base2 == 0.0f));
    pact[1] = s.action; plp[1] = s.lp; plpm[1] = s.lpm; prev = s.action;
  }
  {  // p = 3: divide by 5^prev, thresholds 2^(k*log2f(7))
    rbs = (float)((double)rbs * readlane_d(ipw5, prev));
    double x = (double)fmaxf(rbs, 1.0f);
    int tmax = min((int)__popcll(__ballot(x >= thr7)), bu3);
    bool pv = (t <= tmax);
    SampleOut s = sample_pre(pv ? z5f : NEGINF, pv ? es5f : 0.0f, sc5f,
                             pv && (base3 == 0.0f));
    pact[2] = s.action; plp[2] = s.lp; plpm[2] = s.lpm;
  }

  // ================= write outputs (float32, return order) ================
  if (t == 0) {
    size_t Bz = (size_t)B;
    out[b] = (float)so.action;
    if (((B & 3) == 0)) {   // vectorized epilogue (B=16384: always)
      float4 ta4; ta4.x = (float)st2.action; ta4.y = (float)pact[0];
      ta4.z = (float)pact[1]; ta4.w = (float)pact[2];
      *(float4*)(out + Bz + (size_t)b * 4) = ta4;
      float4 sa4; sa4.x = (float)ssp.action; sa4.y = 0.0f;
      sa4.z = 0.0f; sa4.w = 0.0f;
      *(float4*)(out + Bz * 5 + (size_t)b * 4) = sa4;
      float* lp = out + Bz * 9 + (size_t)b * 6;
      float2 a, c, d;
      a.x = so.lp;  a.y = st2.lp;  *(float2*)(lp) = a;
      c.x = plp[0]; c.y = plp[1];  *(float2*)(lp + 2) = c;
      d.x = plp[2]; d.y = ssp.lp;  *(float2*)(lp + 4) = d;
      float* lm = out + Bz * 15 + (size_t)b * 6;
      a.x = so.lpm;  a.y = st2.lpm;  *(float2*)(lm) = a;
      c.x = plpm[0]; c.y = plpm[1];  *(float2*)(lm + 2) = c;
      d.x = plpm[2]; d.y = ssp.lpm;  *(float2*)(lm + 4) = d;
    } else {
      float* ta = out + Bz + (size_t)b * 4;
      ta[0] = (float)st2.action; ta[1] = (float)pact[0];
      ta[2] = (float)pact[1];    ta[3] = (float)pact[2];
      float* sa = out + Bz * 5 + (size_t)b * 4;
      sa[0] = (float)ssp.action; sa[1] = 0.0f; sa[2] = 0.0f; sa[3] = 0.0f;
      float* lp = out + Bz * 9 + (size_t)b * 6;
      lp[0] = so.lp; lp[1] = st2.lp; lp[2] = plp[0];
      lp[3] = plp[1]; lp[4] = plp[2]; lp[5] = ssp.lp;
      float* lm = out + Bz * 15 + (size_t)b * 6;
      lm[0] = so.lpm; lm[1] = st2.lpm; lm[2] = plpm[0];
      lm[3] = plpm[1]; lm[4] = plpm[2]; lm[5] = ssp.lpm;
    }
  }
}

// ---------------------------------------------------------------------------
extern "C" void kernel_launch(void* const* d_in, const int* in_sizes, int n_in,
                              void* d_out, int out_size, void* d_ws,
                              size_t ws_size, hipStream_t stream) {
  const int B = in_sizes[6];                 // remain_buffer_size: [B]
  const int O = in_sizes[1] / B;             // order_mask: [B,O]
  const int T = in_sizes[13] / B;            // sp_tile2_logit: [B,T]
  const int P = in_sizes[12] / (B * T);      // tile_logits: [B,P,T]
  const int L = in_sizes[2] / (B * P);       // tile_remain_budgets: [B,L,P]

  // keys = jax.random.split(jax.random.key(1), 6), threefry-partitionable
  Keys keys;
  for (int j = 0; j < 6; ++j) {
    uint32_t x0 = 0u, x1 = (uint32_t)j;
    tf2x32(0u, 1u, x0, x1);
    keys.k[2 * j]     = x0;
    keys.k[2 * j + 1] = x1;
  }

  const int wavesPerBlock = 4;
  dim3 block(wavesPerBlock * 64);
  dim3 grid((B + wavesPerBlock - 1) / wavesPerBlock);
  pt_kernel<<<grid, block, 0, stream>>>(
      (const int*)d_in[5],            // loop_ind
      (const float*)d_in[1],          // order_mask
      (const int*)d_in[2],            // tile_remain_budgets
      (const float*)d_in[3],          // tile_masks
      (const float*)d_in[6],          // remain_buffer_size
      (const int*)d_in[7],            // tile2_max
      (const float*)d_in[8],          // max_temporal_tile2
      (const int*)d_in[9],            // sp_tile2_max
      (const int*)d_in[10],           // sp_tile2_min
      (const float*)d_in[11],         // order_logit
      (const float*)d_in[12],         // tile_logits
      (const float*)d_in[13],         // sp_tile2_logit
      (float*)d_out, B, O, T, P, L, keys);
}

// Round 5
// 203.094 us; speedup vs baseline: 1.4866x; 1.0186x over previous
//
#include <hip/hip_runtime.h>
#include <stdint.h>
#include <math.h>

// ---------------------------------------------------------------------------
// JAX threefry2x32 (exact port of jax/_src/prng.py), usable on host + device.
// ---------------------------------------------------------------------------
__host__ __device__ static inline void tf2x32(uint32_t k0, uint32_t k1,
                                              uint32_t& x0, uint32_t& x1) {
  uint32_t ks2 = k0 ^ k1 ^ 0x1BD11BDAu;
  x0 += k0; x1 += k1;
#define TFR(r) { x0 += x1; x1 = (x1 << (r)) | (x1 >> (32 - (r))); x1 ^= x0; }
  TFR(13) TFR(15) TFR(26) TFR(6)
  x0 += k1;  x1 += ks2 + 1u;
  TFR(17) TFR(29) TFR(16) TFR(24)
  x0 += ks2; x1 += k0 + 2u;
  TFR(13) TFR(15) TFR(26) TFR(6)
  x0 += k0;  x1 += k1 + 3u;
  TFR(17) TFR(29) TFR(16) TFR(24)
  x0 += k1;  x1 += ks2 + 4u;
  TFR(13) TFR(15) TFR(26) TFR(6)
  x0 += ks2; x1 += k0 + 5u;
#undef TFR
}

struct Keys { uint32_t k[12]; };   // 6 subkeys (hi, lo) pairs

struct SampleOut { int action; float lp; float lpm; };

// ---------------------------------------------------------------------------
// constexpr tables: thresholds T[k] = 2^(k * l2p) and inverse prime powers.
// tmax = floor(log2(x)/l2p) = #{k in 1..63 : T[k] <= x}  (x >= 1).
// ---------------------------------------------------------------------------
struct DTab { double v[64]; };

constexpr double CEXP2(double w) {           // w >= 0
  long i = (long)w;                          // floor (w >= 0)
  double f = w - (double)i;
  double y = f * 0.69314718055994530941723212145818;  // ln2
  double term = 1.0, sum = 1.0;
  for (int k = 1; k <= 18; ++k) { term = term * y / (double)k; sum += term; }
  double p = 1.0;
  for (long k = 0; k < i; ++k) p *= 2.0;     // exact
  return sum * p;
}
constexpr DTab make_thresh(double l2p) {
  DTab t{};
  t.v[0] = 1e300;                            // lane 0 never counts
  for (int k = 1; k < 64; ++k) t.v[k] = CEXP2((double)k * l2p);
  return t;
}
constexpr DTab make_invpw(int p) {
  DTab t{};
  double pw = 1.0;
  for (int k = 0; k < 64; ++k) { t.v[k] = 1.0 / pw; pw *= (double)p; }
  return t;
}
// float32-rounded np.log2(prime) divisors (JAX x64-disabled demotion)
__constant__ DTab THR3 = make_thresh((double)1.5849625007211562f);  // log2(3)
__constant__ DTab THR5 = make_thresh((double)2.321928094887362f);   // log2(5)
__constant__ DTab THR7 = make_thresh((double)2.807354922057604f);   // log2(7)
__constant__ DTab IPW2 = make_invpw(2);
__constant__ DTab IPW3 = make_invpw(3);
__constant__ DTab IPW5 = make_invpw(5);

// ---------------------------------------------------------------------------
// DPP wave64 primitives. Reductions: row_shr 1/2/4/8 + row_bcast 15/31,
// lane 63 holds result. Inclusive scans (rocPRIM pattern): row_shr 1/2/4/8
// (rows of 16), then row_bcast:15 applied to rows 1,3 (row_mask 0xa), then
// row_bcast:31 applied to rows 2,3 (row_mask 0xc). Pure VALU, no DS pipe.
// ---------------------------------------------------------------------------
#define NEGINF_I 0xff800000            // bit pattern of -inf (max identity)

template <int CTRL, int RMASK>
__device__ __forceinline__ float dpp_max_step(float v) {
  int o = __builtin_amdgcn_update_dpp((int)NEGINF_I, __float_as_int(v),
                                      CTRL, RMASK, 0xf, false);
  return fmaxf(v, __int_as_float(o));
}
template <int CTRL, int RMASK>
__device__ __forceinline__ float dpp_add_step(float v) {
  int o = __builtin_amdgcn_update_dpp(0, __float_as_int(v),
                                      CTRL, RMASK, 0xf, false);
  return v + __int_as_float(o);
}
__device__ __forceinline__ float wave_max_bcast(float v) {   // full reduce
  v = dpp_max_step<0x111, 0xf>(v);
  v = dpp_max_step<0x112, 0xf>(v);
  v = dpp_max_step<0x114, 0xf>(v);
  v = dpp_max_step<0x118, 0xf>(v);
  v = dpp_max_step<0x142, 0xf>(v);
  v = dpp_max_step<0x143, 0xf>(v);
  return __int_as_float(__builtin_amdgcn_readlane(__float_as_int(v), 63));
}
__device__ __forceinline__ float wave_sum_bcast(float v) {   // full reduce
  v = dpp_add_step<0x111, 0xf>(v);
  v = dpp_add_step<0x112, 0xf>(v);
  v = dpp_add_step<0x114, 0xf>(v);
  v = dpp_add_step<0x118, 0xf>(v);
  v = dpp_add_step<0x142, 0xf>(v);
  v = dpp_add_step<0x143, 0xf>(v);
  return __int_as_float(__builtin_amdgcn_readlane(__float_as_int(v), 63));
}
__device__ __forceinline__ float wave_prefix_max(float v) {  // inclusive scan
  v = dpp_max_step<0x111, 0xf>(v);
  v = dpp_max_step<0x112, 0xf>(v);
  v = dpp_max_step<0x114, 0xf>(v);
  v = dpp_max_step<0x118, 0xf>(v);
  v = dpp_max_step<0x142, 0xa>(v);   // lane15 -> row1, lane47 -> row3
  v = dpp_max_step<0x143, 0xc>(v);   // lane31 -> rows 2,3
  return v;
}
__device__ __forceinline__ float wave_prefix_sum(float v) {  // inclusive scan
  v = dpp_add_step<0x111, 0xf>(v);
  v = dpp_add_step<0x112, 0xf>(v);
  v = dpp_add_step<0x114, 0xf>(v);
  v = dpp_add_step<0x118, 0xf>(v);
  v = dpp_add_step<0x142, 0xa>(v);
  v = dpp_add_step<0x143, 0xc>(v);
  return v;
}

__device__ __forceinline__ float readlane_f(float v, int lane) {
  return __int_as_float(__builtin_amdgcn_readlane(__float_as_int(v), lane));
}
__device__ __forceinline__ double readlane_d(double v, int lane) {
  union { double d; int i[2]; } u, r;
  u.d = v;
  r.i[0] = __builtin_amdgcn_readlane(u.i[0], lane);
  r.i[1] = __builtin_amdgcn_readlane(u.i[1], lane);
  return r.d;
}

// ---------------------------------------------------------------------------
// Full-width categorical sample (used for sp: two-sided mask, independent).
// ---------------------------------------------------------------------------
__device__ static inline SampleOut sample_full(float z, float es, float sc_full,
                                               bool lpm_pred) {
  float zmax = wave_max_bcast(z);
  unsigned long long ball = __ballot(z == zmax);
  int action = __builtin_amdgcn_readfirstlane(__ffsll(ball) - 1);
  float essum = wave_sum_bcast(es);
  float sa = readlane_f(sc_full, action);
  unsigned long long mb = __ballot(lpm_pred);
  SampleOut r;
  r.action = action;
  r.lp = sa - __logf(essum);
  r.lpm = (__popcll(mb) > 1) ? 1.0f : 0.0f;
  return r;
}

// gumbel from threefry block (0, flat_idx), bits = x0 ^ x1 (partitionable)
__device__ static inline float gumbel_f(uint32_t k0, uint32_t k1,
                                        uint32_t flat_idx) {
  uint32_t x0 = 0u, x1 = flat_idx;
  tf2x32(k0, k1, x0, x1);
  uint32_t bits = x0 ^ x1;
  uint32_t fb = (bits >> 9) | 0x3f800000u;
  float f = __uint_as_float(fb) - 1.0f;                 // [0, 1-2^-23]
  const float tinyf = 1.1754943508222875e-38f;          // f32 tiny
  float u = fmaxf(tinyf, f + tinyf);                    // jax.random.uniform
  return -__logf(-__logf(u));                           // v_log_f32 x2
}

// ---------------------------------------------------------------------------
// Main kernel: one wave per batch row. 4 waves / 256-thread block.
// ---------------------------------------------------------------------------
__global__ __launch_bounds__(256) void pt_kernel(
    const int*   __restrict__ loop_ind_p,          // [1]
    const float* __restrict__ order_mask,          // [B,O]
    const int*   __restrict__ tile_remain_budgets, // [B,L,P]
    const float* __restrict__ tile_masks,          // [B,L,P,T]
    const float* __restrict__ remain_buffer_size,  // [B]
    const int*   __restrict__ tile2_max,           // [B]
    const float* __restrict__ max_temporal_tile2,  // [B]
    const int*   __restrict__ sp_tile2_max,        // [B]
    const int*   __restrict__ sp_tile2_min,        // [B]
    const float* __restrict__ order_logit,         // [B,O]
    const float* __restrict__ tile_logits,         // [B,P,T]
    const float* __restrict__ sp_tile2_logit,      // [B,T]
    float*       __restrict__ out,                 // [21*B]
    int B, int O, int T, int P, int L, Keys keys) {
  const int wave = threadIdx.x >> 6;
  const int t    = threadIdx.x & 63;
  const int b    = blockIdx.x * (blockDim.x >> 6) + wave;
  if (b >= B) return;
  // wave-uniform row index in SGPR -> scalar loads for row scalars
  const int bs = __builtin_amdgcn_readfirstlane(b);

  const float NEGINF = -__builtin_inff();
  const int li = loop_ind_p[0];

  // ================= per-lane constant tables ==============================
  double thr3 = THR3.v[t], thr5 = THR5.v[t], thr7 = THR7.v[t];
  double ipw2 = IPW2.v[t], ipw3 = IPW3.v[t], ipw5 = IPW5.v[t];

  // ================= action-independent precompute (full ILP) =============
  float g0 = gumbel_f(keys.k[0],  keys.k[1],  (uint32_t)(bs * O + t));
  uint32_t fT = (uint32_t)(bs * T + t);
  float g1 = gumbel_f(keys.k[2],  keys.k[3],  fT);   // sp
  float g2 = gumbel_f(keys.k[4],  keys.k[5],  fT);   // tile2
  float g3 = gumbel_f(keys.k[6],  keys.k[7],  fT);   // p=1
  float g4 = gumbel_f(keys.k[8],  keys.k[9],  fT);   // p=2
  float g5 = gumbel_f(keys.k[10], keys.k[11], fT);   // p=3

  float om  = (t < O) ? order_mask[(size_t)bs * O + t] : 1.0f;
  float osc = (t < O) ? (order_logit[(size_t)bs * O + t] + om) : NEGINF;

  const float* tm_row = tile_masks + ((size_t)bs * L + li) * P * T;
  const float* tl_row = tile_logits + (size_t)bs * P * T;
  float base0 = tm_row[t];
  float base1 = tm_row[T + t];
  float base2 = tm_row[2 * T + t];
  float base3 = tm_row[3 * T + t];

  int spmx = sp_tile2_max[bs], spmn = sp_tile2_min[bs];
  float spmask = (t > spmx || t < spmn) ? NEGINF : base0;
  float spsc   = sp_tile2_logit[(size_t)bs * T + t] + spmask;

  float sc2f = tl_row[t]         + base0;   // tile2 (p=0)
  float sc3f = tl_row[T + t]     + base1;   // p=1
  float sc4f = tl_row[2 * T + t] + base2;   // p=2
  float sc5f = tl_row[3 * T + t] + base3;   // p=3
  float es2f = __expf(sc2f), es3f = __expf(sc3f);
  float es4f = __expf(sc4f), es5f = __expf(sc5f);
  float z2f = sc2f + g2, z3f = sc3f + g3, z4f = sc4f + g4, z5f = sc5f + g5;

  // prefix structures for the action-dependent stages (all off-chain):
  float ps2 = wave_prefix_sum(es2f);                 // tile2 range-sum
  float pm3 = wave_prefix_max(z3f), ps3 = wave_prefix_sum(es3f);
  float pm4 = wave_prefix_max(z4f), ps4 = wave_prefix_sum(es4f);
  float pm5 = wave_prefix_max(z5f), ps5 = wave_prefix_sum(es5f);

  const int* budg = tile_remain_budgets + ((size_t)bs * L + li) * P;
  int bu1 = budg[1], bu2 = budg[2], bu3 = budg[3];
  int t2maxcap = tile2_max[bs];
  int mt = (int)max_temporal_tile2[bs];     // trunc toward zero, >= 0
  float rbs = remain_buffer_size[bs];

  // ================= order sample (O=7: 8-lane mini-reduce, no deps) ======
  SampleOut so;
  {
    float z0 = osc + g0;                    // -inf beyond O
    float es0 = __expf(osc);                // 0 beyond O
    float mv = z0, sv = es0;
    mv = dpp_max_step<0x111, 0xf>(mv);
    mv = dpp_max_step<0x112, 0xf>(mv);
    mv = dpp_max_step<0x114, 0xf>(mv);      // lane 7 = max(lanes 0..7)
    sv = dpp_add_step<0x111, 0xf>(sv);
    sv = dpp_add_step<0x112, 0xf>(sv);
    sv = dpp_add_step<0x114, 0xf>(sv);      // lane 7 = sum(lanes 0..7)
    float zmax = readlane_f(mv, 7);
    unsigned long long ball = __ballot(z0 == zmax);
    so.action = __builtin_amdgcn_readfirstlane(__ffsll(ball) - 1);
    float essum = readlane_f(sv, 7);
    so.lp = readlane_f(osc, so.action) - __logf(essum);
    unsigned long long mb = __ballot((t < O) && (om == 0.0f));
    so.lpm = (__popcll(mb) > 1) ? 1.0f : 0.0f;
  }

  // ================= sp sample (independent, two-sided mask) ==============
  SampleOut ssp = sample_full(spsc + g1, __expf(spsc), spsc, spmask == 0.0f);

  // ================= tile2 sample (depends on sp action) ==================
  SampleOut st2;
  {
    int t2min = ssp.action;
    int t2mx = min(t2maxcap, t2min + mt);
    bool pv2 = (t <= t2mx) && (t >= t2min);
    float zm2 = pv2 ? z2f : NEGINF;
    float zmax = wave_max_bcast(zm2);              // only on-chain reduce
    unsigned long long ball = __ballot(zm2 == zmax);
    st2.action = __builtin_amdgcn_readfirstlane(__ffsll(ball) - 1);
    float hi = readlane_f(ps2, t2mx);
    float lo = readlane_f(ps2, max(t2min - 1, 0));
    float essum = hi - ((t2min > 0) ? lo : 0.0f);  // prefix range-sum
    st2.lp = readlane_f(sc2f, st2.action) - __logf(essum);
    unsigned long long mb = __ballot(pv2 && (base0 == 0.0f));
    st2.lpm = (__popcll(mb) > 1) ? 1.0f : 0.0f;
  }

  // ================= p = 1..3 chain (prefix readlanes only) ===============
  int   pact[3];
  float plp[3], plpm[3];
  int prev = st2.action;
#define P_STAGE(IDX, IPW, THR, BU, PM, PS, ZF, SCF, BASE)                    \
  {                                                                          \
    rbs = (float)((double)rbs * readlane_d(IPW, prev));                      \
    double x = (double)fmaxf(rbs, 1.0f);                                     \
    int tmax = min((int)__popcll(__ballot(x >= THR)), BU);                   \
    float zmax = readlane_f(PM, tmax);                                       \
    unsigned long long ball = __ballot((ZF == zmax) && (t <= tmax));         \
    int act = __builtin_amdgcn_readfirstlane(__ffsll(ball) - 1);             \
    float essum = readlane_f(PS, tmax);                                      \
    pact[IDX] = act;                                                         \
    plp[IDX]  = readlane_f(SCF, act) - __logf(essum);                        \
    unsigned long long mb = __ballot((t <= tmax) && (BASE == 0.0f));         \
    plpm[IDX] = (__popcll(mb) > 1) ? 1.0f : 0.0f;                            \
    prev = act;                                                              \
  }
  P_STAGE(0, ipw2, thr3, bu1, pm3, ps3, z3f, sc3f, base1)
  P_STAGE(1, ipw3, thr5, bu2, pm4, ps4, z4f, sc4f, base2)
  P_STAGE(2, ipw5, thr7, bu3, pm5, ps5, z5f, sc5f, base3)
#undef P_STAGE

  // ================= write outputs (float32, return order) ================
  if (t == 0) {
    size_t Bz = (size_t)B;
    out[b] = (float)so.action;
    float4 ta4; ta4.x = (float)st2.action; ta4.y = (float)pact[0];
    ta4.z = (float)pact[1]; ta4.w = (float)pact[2];
    *(float4*)(out + Bz + (size_t)b * 4) = ta4;
    float4 sa4; sa4.x = (float)ssp.action; sa4.y = 0.0f;
    sa4.z = 0.0f; sa4.w = 0.0f;
    *(float4*)(out + Bz * 5 + (size_t)b * 4) = sa4;
    float* lp = out + Bz * 9 + (size_t)b * 6;
    float2 a, c, d;
    a.x = so.lp;  a.y = st2.lp;  *(float2*)(lp) = a;
    c.x = plp[0]; c.y = plp[1];  *(float2*)(lp + 2) = c;
    d.x = plp[2]; d.y = ssp.lp;  *(float2*)(lp + 4) = d;
    float* lm = out + Bz * 15 + (size_t)b * 6;
    a.x = so.lpm;  a.y = st2.lpm;  *(float2*)(lm) = a;
    c.x = plpm[0]; c.y = plpm[1];  *(float2*)(lm + 2) = c;
    d.x = plpm[2]; d.y = ssp.lpm;  *(float2*)(lm + 4) = d;
  }
}

// ---------------------------------------------------------------------------
extern "C" void kernel_launch(void* const* d_in, const int* in_sizes, int n_in,
                              void* d_out, int out_size, void* d_ws,
                              size_t ws_size, hipStream_t stream) {
  const int B = in_sizes[6];                 // remain_buffer_size: [B]
  const int O = in_sizes[1] / B;             // order_mask: [B,O]
  const int T = in_sizes[13] / B;            // sp_tile2_logit: [B,T]
  const int P = in_sizes[12] / (B * T);      // tile_logits: [B,P,T]
  const int L = in_sizes[2] / (B * P);       // tile_remain_budgets: [B,L,P]

  // keys = jax.random.split(jax.random.key(1), 6), threefry-partitionable
  Keys keys;
  for (int j = 0; j < 6; ++j) {
    uint32_t x0 = 0u, x1 = (uint32_t)j;
    tf2x32(0u, 1u, x0, x1);
    keys.k[2 * j]     = x0;
    keys.k[2 * j + 1] = x1;
  }

  const int wavesPerBlock = 4;
  dim3 block(wavesPerBlock * 64);
  dim3 grid((B + wavesPerBlock - 1) / wavesPerBlock);
  pt_kernel<<<grid, block, 0, stream>>>(
      (const int*)d_in[5],            // loop_ind
      (const float*)d_in[1],          // order_mask
      (const int*)d_in[2],            // tile_remain_budgets
      (const float*)d_in[3],          // tile_masks
      (const float*)d_in[6],          // remain_buffer_size
      (const int*)d_in[7],            // tile2_max
      (const float*)d_in[8],          // max_temporal_tile2
      (const int*)d_in[9],            // sp_tile2_max
      (const int*)d_in[10],           // sp_tile2_min
      (const float*)d_in[11],         // order_logit
      (const float*)d_in[12],         // tile_logits
      (const float*)d_in[13],         // sp_tile2_logit
      (float*)d_out, B, O, T, P, L, keys);
}